// Round 11
// baseline (103.063 us; speedup 1.0000x reference)
//
#include <hip/hip_runtime.h>

// CoLL fused, 2 dispatches, NO atomics:
//  A) reduce_k : per-block min/max partials -> d_ws (2048 float2)
//  B) coll_k   : partial-reduce prologue, then fused 3x3 stencil, branchless
//     taps, batched loads. 2048 blocks x 4 images (occupancy 2x vs R10).
//     y(p,c) = sum_{3x3} w[dq] * x(q,c) * co[bin(p,c), bin(q,c)]
// N=8, H=128, W=128, C=64, NUM_BINS=8. One image = 128*128*16 = 262144 float4.

static constexpr int IMG4 = 128 * 128 * 16;
static constexpr int TOT4 = 8 * IMG4;            // 2097152 float4
static constexpr int RBLK = 2048;                // reduce blocks
static constexpr int RSTRIDE = RBLK * 256;       // 524288; TOT4/RSTRIDE = 4
static constexpr int CBLK = 2048, NTHR = 256;    // coll grid: 2 blocks per ofs-slice
static constexpr int ZROW = 576;                 // zeroed cw row for invalid taps

__device__ __forceinline__ int qbin(float v, float xmin, float scale) {
    float t = (v - xmin) * scale;   // >= 0 exactly (v >= xmin in f32)
    t = fminf(t, 7.0f);
    return (int)t;                  // trunc == floor for t >= 0
}

__global__ __launch_bounds__(256) void reduce_k(const float4* __restrict__ x4,
                                                float2* __restrict__ part) {
    const int i = blockIdx.x * 256 + threadIdx.x;
    float4 a = x4[i];
    float4 b = x4[i + RSTRIDE];
    float4 c = x4[i + 2 * RSTRIDE];
    float4 d = x4[i + 3 * RSTRIDE];
    float lmin = fminf(fminf(fminf(a.x, a.y), fminf(a.z, a.w)),
                       fminf(fminf(b.x, b.y), fminf(b.z, b.w)));
    float lmax = fmaxf(fmaxf(fmaxf(a.x, a.y), fmaxf(a.z, a.w)),
                       fmaxf(fmaxf(b.x, b.y), fmaxf(b.z, b.w)));
    lmin = fminf(lmin, fminf(fminf(fminf(c.x, c.y), fminf(c.z, c.w)),
                             fminf(fminf(d.x, d.y), fminf(d.z, d.w))));
    lmax = fmaxf(lmax, fmaxf(fmaxf(fmaxf(c.x, c.y), fmaxf(c.z, c.w)),
                             fmaxf(fmaxf(d.x, d.y), fmaxf(d.z, d.w))));
#pragma unroll
    for (int off = 32; off; off >>= 1) {
        lmin = fminf(lmin, __shfl_xor(lmin, off, 64));
        lmax = fmaxf(lmax, __shfl_xor(lmax, off, 64));
    }
    __shared__ float smin[4], smax[4];
    const int wid = threadIdx.x >> 6, lane = threadIdx.x & 63;
    if (lane == 0) { smin[wid] = lmin; smax[wid] = lmax; }
    __syncthreads();
    if (threadIdx.x == 0) {
        part[blockIdx.x] = make_float2(
            fminf(fminf(smin[0], smin[1]), fminf(smin[2], smin[3])),
            fmaxf(fmaxf(smax[0], smax[1]), fmaxf(smax[2], smax[3])));
    }
}

__global__ __launch_bounds__(256) void coll_k(const float4* __restrict__ x4,
                                              const float* __restrict__ co,
                                              const float* __restrict__ wsp,
                                              float4* __restrict__ y4,
                                              const float2* __restrict__ part) {
    __shared__ float co_s[64], w_s[9];
    __shared__ float cw[640];      // rows 0..8: w[tap]*co[r][c]; row 9: zeros
    __shared__ float sred[8];

    if (threadIdx.x < 64) co_s[threadIdx.x] = co[threadIdx.x];
    if (threadIdx.x < 9)  w_s[threadIdx.x] = wsp[threadIdx.x];

    // prologue: every block redundantly reduces the 2048 partials (16 KB, L2-hot)
    float gmin = 3.4028235e38f, gmax = -3.4028235e38f;
#pragma unroll
    for (int j = 0; j < 8; ++j) {
        float2 p = part[threadIdx.x * 8 + j];
        gmin = fminf(gmin, p.x);
        gmax = fmaxf(gmax, p.y);
    }
#pragma unroll
    for (int off = 32; off; off >>= 1) {
        gmin = fminf(gmin, __shfl_xor(gmin, off, 64));
        gmax = fmaxf(gmax, __shfl_xor(gmax, off, 64));
    }
    const int wid = threadIdx.x >> 6, lane = threadIdx.x & 63;
    if (lane == 0) { sred[wid] = gmin; sred[4 + wid] = gmax; }
    __syncthreads();

#pragma unroll
    for (int idx = threadIdx.x; idx < 640; idx += 256)
        cw[idx] = (idx < 576) ? w_s[idx >> 6] * co_s[idx & 63] : 0.0f;

    const float xmin = fminf(fminf(sred[0], sred[1]), fminf(sred[2], sred[3]));
    const float xmax = fmaxf(fmaxf(sred[4], sred[5]), fmaxf(sred[6], sred[7]));
    const float scale = 8.0f / ((xmax - xmin) + 1e-8f);
    __syncthreads();   // cw ready

    // block -> (image half, ofs slice): adjacent blocks share halo rows
    const int half = blockIdx.x & 1;                       // images 0-3 / 4-7
    const int ofs = (blockIdx.x >> 1) * 256 + threadIdx.x; // within-image idx
    const int w = (ofs >> 4) & 127;
    const int h = (ofs >> 11) & 127;
    const bool wm = (w > 0), wp = (w < 127), hm = (h > 0), hp = (h < 127);

    const bool v0 = hm && wm, v1 = hm, v2 = hm && wp;
    const bool v3 = wm,                v5 = wp;
    const bool v6 = hp && wm, v7 = hp, v8 = hp && wp;
    const int r0 = v0 ? 0 * 64 : ZROW, r1 = v1 ? 1 * 64 : ZROW;
    const int r2 = v2 ? 2 * 64 : ZROW, r3 = v3 ? 3 * 64 : ZROW;
    const int r5 = v5 ? 5 * 64 : ZROW, r6 = v6 ? 6 * 64 : ZROW;
    const int r7 = v7 ? 7 * 64 : ZROW, r8 = v8 ? 8 * 64 : ZROW;

#pragma unroll 1
    for (int j = 0; j < 4; ++j) {
        const int base = (half * 4 + j) * IMG4 + ofs;

        // ---- phase A: issue all 9 loads (branchless, clamped) ----
        const float4 qc = x4[base];
        const float4 q0 = x4[v0 ? base - 2064 : base];
        const float4 q1 = x4[v1 ? base - 2048 : base];
        const float4 q2 = x4[v2 ? base - 2032 : base];
        const float4 q3 = x4[v3 ? base - 16   : base];
        const float4 q5 = x4[v5 ? base + 16   : base];
        const float4 q6 = x4[v6 ? base + 2032 : base];
        const float4 q7 = x4[v7 ? base + 2048 : base];
        const float4 q8 = x4[v8 ? base + 2064 : base];

        // ---- phase B: center bins ----
        const int bx = qbin(qc.x, xmin, scale), ipx = bx * 8;
        const int by = qbin(qc.y, xmin, scale), ipy = by * 8;
        const int bz = qbin(qc.z, xmin, scale), ipz = bz * 8;
        const int bw = qbin(qc.w, xmin, scale), ipw = bw * 8;

        float ax = qc.x * cw[4 * 64 + ipx + bx];
        float ay = qc.y * cw[4 * 64 + ipy + by];
        float az = qc.z * cw[4 * 64 + ipz + bz];
        float aw = qc.w * cw[4 * 64 + ipw + bw];

#define ACC(Q, R) { \
        ax = fmaf(Q.x, cw[(R) + ipx + qbin(Q.x, xmin, scale)], ax); \
        ay = fmaf(Q.y, cw[(R) + ipy + qbin(Q.y, xmin, scale)], ay); \
        az = fmaf(Q.z, cw[(R) + ipz + qbin(Q.z, xmin, scale)], az); \
        aw = fmaf(Q.w, cw[(R) + ipw + qbin(Q.w, xmin, scale)], aw); }

        ACC(q0, r0) ACC(q1, r1) ACC(q2, r2)
        ACC(q3, r3)             ACC(q5, r5)
        ACC(q6, r6) ACC(q7, r7) ACC(q8, r8)
#undef ACC

        y4[base] = make_float4(ax, ay, az, aw);
    }
}

extern "C" void kernel_launch(void* const* d_in, const int* in_sizes, int n_in,
                              void* d_out, int out_size, void* d_ws, size_t ws_size,
                              hipStream_t stream) {
    const float4* x4 = (const float4*)d_in[0];
    const float*  co = (const float*)d_in[1];
    const float*  wsp = (const float*)d_in[2];
    float4* y4 = (float4*)d_out;
    float2* part = (float2*)d_ws;    // 2048 float2 = 16 KB scratch

    hipLaunchKernelGGL(reduce_k, dim3(RBLK), dim3(NTHR), 0, stream, x4, part);
    hipLaunchKernelGGL(coll_k, dim3(CBLK), dim3(NTHR), 0, stream,
                       x4, co, wsp, y4, part);
}